// Round 9
// baseline (243.136 us; speedup 1.0000x reference)
//
#include <hip/hip_runtime.h>
#include <stdint.h>

typedef unsigned short u16;
typedef unsigned int u32;

#define NROWS 1024
#define DDIM  1024
#define SLEN  64
#define BATCH 64
#define VOCAB 32000
#define NBN   250            // 128-wide column blocks
#define PAD_WORD 1

typedef __attribute__((ext_vector_type(4))) float f32x4;
typedef __attribute__((ext_vector_type(8))) short s16x8;

__device__ __forceinline__ u16 f2bf(float x) {
  union { float f; u32 u; } v; v.f = x;
  u32 r = v.u + 0x7FFF + ((v.u >> 16) & 1);   // RNE
  return (u16)(r >> 16);
}
__device__ __forceinline__ float bf2f(u16 x) {
  union { u32 u; float f; } v; v.u = ((u32)x) << 16;
  return v.f;
}
// packed f32 pair -> bf16x2 in one instruction (RNE)
__device__ __forceinline__ u32 cvtpk(float a, float b) {
  u32 r;
  asm volatile("v_cvt_pk_bf16_f32 %0, %1, %2" : "=v"(r) : "v"(a), "v"(b));
  return r;
}

// ---------------- kernel 1: p_copy + hidden -> bf16 ----------------
__global__ __launch_bounds__(256) void prep_kernel(
    const float* __restrict__ hidden, const float* __restrict__ w_copy,
    const float* __restrict__ b_copy, u16* __restrict__ hbf,
    float* __restrict__ pcopy)
{
  const int n = blockIdx.x;
  const int tid = threadIdx.x;
  float4 h = ((const float4*)(hidden + (size_t)n * DDIM))[tid];
  float4 w = ((const float4*)w_copy)[tid];
  ushort4 hb;
  hb.x = f2bf(h.x); hb.y = f2bf(h.y); hb.z = f2bf(h.z); hb.w = f2bf(h.w);
  ((ushort4*)(hbf + (size_t)n * DDIM))[tid] = hb;
  float d = h.x * w.x + h.y * w.y + h.z * w.z + h.w * w.w;
  #pragma unroll
  for (int m = 1; m < 64; m <<= 1) d += __shfl_xor(d, m);
  __shared__ float ws4[4];
  if ((tid & 63) == 0) ws4[tid >> 6] = d;
  __syncthreads();
  if (tid == 0) {
    float s = ws4[0] + ws4[1] + ws4[2] + ws4[3] + b_copy[0];
    pcopy[n] = 1.0f / (1.0f + __expf(-s));
  }
}

// -------- kernel 2: 128x128 bf16 GEMM, 4 waves, BK=64, 2 blocks/CU.
//          B read as f32 W (reg-staged + v_cvt_pk), A via global_load_lds.
//          r5-proven wait shape; 1 barrier / K-tile. exp epilogue. ----
__global__ __launch_bounds__(256, 2) void gemm_exp_kernel(
    const u16* __restrict__ A, const float* __restrict__ Wf,
    float* __restrict__ out, u16* __restrict__ ebf,
    float* __restrict__ partial, const int use_bf16)
{
  __shared__ u16 lAs[2][8192];     // 128 rows x 64 cols bf16, XOR-swizzled slots
  __shared__ u16 lBs[2][8192];
  __shared__ float rowacc[2][128];

  const int tid  = threadIdx.x;
  const int lane = tid & 63;
  const int wid  = tid >> 6;        // 0..3
  const int wm   = wid >> 1;        // 0..1 (M)
  const int wn   = wid & 1;         // 0..1 (N)
  const int al   = lane & 15;
  const int ks   = lane >> 4;       // 0..3

  // XCD-chunked swizzle, 2000 blocks (2000 % 8 == 0 -> bijective).
  // 8 consecutive swz share bn -> same XCD -> B panel L2 reuse.
  const int orig = blockIdx.x;
  const int swz  = (orig & 7) * 250 + (orig >> 3);
  const int bm   = swz & 7;         // 8 M-blocks of 128
  const int bn   = swz >> 3;        // 250 N-blocks of 128

  const u16* Abase = A + (size_t)(bm * 128) * DDIM;

  // ---- A staging: 4 gload_lds/thread; linear dest, pre-swizzled source ----
  int arow_s[4], acs_s[4], asl_s[4];
  #pragma unroll
  for (int i = 0; i < 4; ++i) {
    const int s = (i * 4 + wid) * 64 + lane;   // 16B slot 0..1023
    asl_s[i]  = s;
    arow_s[i] = s >> 3;                        // 8 slots (128B) per row
    acs_s[i]  = (s & 7) ^ ((s >> 3) & 7);      // source slot, pre-swizzled
  }
#define STAGE_A(lptr, kt) do { \
    _Pragma("unroll") \
    for (int i_ = 0; i_ < 4; ++i_) \
      __builtin_amdgcn_global_load_lds( \
        (const __attribute__((address_space(1))) u32*)(Abase + (size_t)arow_s[i_] * DDIM + (kt) + acs_s[i_] * 8), \
        (__attribute__((address_space(3))) u32*)((lptr) + asl_s[i_] * 8), 16, 0, 0); \
  } while (0)

  // ---- B reg-staging: thread covers row tid>>1, 32 f32 cols (half-row) ----
  const int brow = tid >> 1;            // 0..127
  const int bch  = tid & 1;             // which 32-col half
  const float* Bsrc = Wf + (size_t)(bn * 128 + brow) * DDIM + bch * 32;
  f32x4 br[8];
#define ISSUE_B(kt) do { \
    _Pragma("unroll") \
    for (int j_ = 0; j_ < 8; ++j_) br[j_] = *(const f32x4*)(Bsrc + (kt) + j_ * 4); \
  } while (0)

  union pk8 { u32 w[4]; s16x8 v; };
#define CVT_WRITE_B(dst) do { \
    _Pragma("unroll") \
    for (int q_ = 0; q_ < 4; ++q_) { \
      pk8 p_; \
      p_.w[0] = cvtpk(br[2*q_].x,   br[2*q_].y); \
      p_.w[1] = cvtpk(br[2*q_].z,   br[2*q_].w); \
      p_.w[2] = cvtpk(br[2*q_+1].x, br[2*q_+1].y); \
      p_.w[3] = cvtpk(br[2*q_+1].z, br[2*q_+1].w); \
      const int sl_ = (bch * 4 + q_) ^ (brow & 7); \
      *(s16x8*)((dst) + brow * 64 + sl_ * 8) = p_.v; \
    } } while (0)

#define WL(n) do { asm volatile("s_waitcnt lgkmcnt(" #n ")" ::: "memory"); \
                   __builtin_amdgcn_sched_barrier(0); } while (0)
#define WV(n) do { asm volatile("s_waitcnt vmcnt(" #n ")" ::: "memory"); \
                   __builtin_amdgcn_sched_barrier(0); } while (0)
#define BAR() do { __builtin_amdgcn_sched_barrier(0); \
                   __builtin_amdgcn_s_barrier(); \
                   __builtin_amdgcn_sched_barrier(0); } while (0)

#define RD_A(buf) do { \
    _Pragma("unroll") \
    for (int mi = 0; mi < 4; ++mi) { \
      const int r_ = wm * 64 + mi * 16 + al; \
      const u16* p_ = (buf) + r_ * 64; \
      af[mi][0] = *(const s16x8*)(p_ + ((ks)     ^ (r_ & 7)) * 8); \
      af[mi][1] = *(const s16x8*)(p_ + ((4 + ks) ^ (r_ & 7)) * 8); \
    } } while (0)
#define RD_BLO(buf) do { \
    _Pragma("unroll") \
    for (int ni = 0; ni < 2; ++ni) { \
      const int r_ = wn * 64 + ni * 16 + al; \
      const u16* p_ = (buf) + r_ * 64; \
      bl[ni][0] = *(const s16x8*)(p_ + ((ks)     ^ (r_ & 7)) * 8); \
      bl[ni][1] = *(const s16x8*)(p_ + ((4 + ks) ^ (r_ & 7)) * 8); \
    } } while (0)
#define RD_BHI(buf) do { \
    _Pragma("unroll") \
    for (int ni = 0; ni < 2; ++ni) { \
      const int r_ = wn * 64 + 32 + ni * 16 + al; \
      const u16* p_ = (buf) + r_ * 64; \
      bh[ni][0] = *(const s16x8*)(p_ + ((ks)     ^ (r_ & 7)) * 8); \
      bh[ni][1] = *(const s16x8*)(p_ + ((4 + ks) ^ (r_ & 7)) * 8); \
    } } while (0)
#define MM(BF, c0) do { \
    __builtin_amdgcn_s_setprio(1); \
    _Pragma("unroll") \
    for (int mi = 0; mi < 4; ++mi) \
      _Pragma("unroll") \
      for (int ni = 0; ni < 2; ++ni) \
        _Pragma("unroll") \
        for (int kk = 0; kk < 2; ++kk) \
          acc[mi][(c0) + ni] = __builtin_amdgcn_mfma_f32_16x16x32_bf16( \
              af[mi][kk], BF[ni][kk], acc[mi][(c0) + ni], 0, 0, 0); \
    __builtin_amdgcn_s_setprio(0); \
  } while (0)

  u16* lAc = &lAs[0][0]; u16* lBc = &lBs[0][0];
  u16* lAn = &lAs[1][0]; u16* lBn = &lBs[1][0];

  // ---- prologue ----
  ISSUE_B(0);                 // vm: [B0 x8]
  STAGE_A(lAc, 0);            // vm: [B0 x8, A0 x4]
  WV(4);                      // B0 regs landed (A0 flying)
  CVT_WRITE_B(lBc);
  ISSUE_B(64);                // vm: [A0 x4, B1 x8]
  WL(0);                      // ds_writes drained
  WV(8);                      // A0 landed (B1 remains)
  BAR();

  f32x4 acc[4][4];
  #pragma unroll
  for (int i = 0; i < 4; ++i)
    #pragma unroll
    for (int j = 0; j < 4; ++j)
      acc[i][j] = (f32x4){0.f, 0.f, 0.f, 0.f};

  s16x8 af[4][2], bl[2][2], bh[2][2];

  for (int t = 0; t < 15; ++t) {
    // entry invariant: vm = [B(t+1) x8]; lgkm empty; cur buffers ready
    RD_A(lAc); RD_BLO(lBc);                 // 12 ds_reads
    STAGE_A(lAn, (t + 1) * 64);             // vm: [B(t+1) 8, A(t+1) 4]
    WV(4);                                  // B(t+1) regs landed (A flying)
    CVT_WRITE_B(lBn);                       // +4 ds_writes (lgkm 16)
    if (t < 14) ISSUE_B((t + 2) * 64);      // vm: [A(t+1) 4, B(t+2) 8]
    WL(4);                                  // all 12 reads done (writes fly)
    MM(bl, 0);
    RD_BHI(lBc);                            // +4 reads (lgkm: 4 wr + 4 rd)
    WL(0);                                  // bhi ready, writes drained
    MM(bh, 2);
    if (t < 14) { WV(8); } else { WV(0); }  // A(t+1) landed (B(t+2) flies)
    BAR();                                  // next buffers ready for all waves
    u16* tp = lAc; lAc = lAn; lAn = tp;
    tp = lBc; lBc = lBn; lBn = tp;
  }
  // ---- final tile t=15 ----
  RD_A(lAc); RD_BLO(lBc);
  WL(0);
  MM(bl, 0);
  RD_BHI(lBc);
  WL(0);
  MM(bh, 2);

#undef STAGE_A
#undef ISSUE_B
#undef CVT_WRITE_B
#undef WL
#undef WV
#undef BAR

  // ---- epilogue: e = exp(logit), write (bf16 or f32), row-sums ----
  const int g = ks;                 // C/D: row = g*4 + j, col = lane&15
  float rsum[4][4];
  #pragma unroll
  for (int mi = 0; mi < 4; ++mi)
    #pragma unroll
    for (int j = 0; j < 4; ++j) rsum[mi][j] = 0.f;

  const size_t grow0 = (size_t)(bm * 128 + wm * 64);
  const int gcol0 = bn * 128 + wn * 64;
  #pragma unroll
  for (int mi = 0; mi < 4; ++mi) {
    #pragma unroll
    for (int j = 0; j < 4; ++j) {
      const size_t row = grow0 + mi * 16 + g * 4 + j;
      #pragma unroll
      for (int ni = 0; ni < 4; ++ni) {
        const int col = gcol0 + ni * 16 + al;
        float e = __expf(acc[mi][ni][j]);
        if (col == PAD_WORD) e = 0.f;
        rsum[mi][j] += e;
        if (use_bf16) ebf[row * VOCAB + col] = f2bf(e);
        else          out[row * VOCAB + col] = e;
      }
    }
  }
  #pragma unroll
  for (int mi = 0; mi < 4; ++mi)
    #pragma unroll
    for (int j = 0; j < 4; ++j) {
      float v = rsum[mi][j];
      v += __shfl_xor(v, 1);
      v += __shfl_xor(v, 2);
      v += __shfl_xor(v, 4);
      v += __shfl_xor(v, 8);
      rsum[mi][j] = v;
    }
  if (al == 0) {
    #pragma unroll
    for (int mi = 0; mi < 4; ++mi)
      #pragma unroll
      for (int j = 0; j < 4; ++j)
        rowacc[wn][wm * 64 + mi * 16 + g * 4 + j] = rsum[mi][j];
  }
  __syncthreads();
  if (tid < 128)
    partial[(size_t)bn * NROWS + bm * 128 + tid] =
        rowacc[0][tid] + rowacc[1][tid];
}

// ---------------- kernel 3: reduce partials -> scale/ofs ----------------
__global__ __launch_bounds__(256) void rowsum_kernel(
    const float* __restrict__ partial, const float* __restrict__ pcopy,
    float* __restrict__ scale, float* __restrict__ ofs)
{
  const int n = blockIdx.x * 256 + threadIdx.x;
  if (n >= NROWS) return;
  float s = 0.f;
  for (int j = 0; j < NBN; ++j) s += partial[(size_t)j * NROWS + n];
  const float p = pcopy[n];
  scale[n] = (1.0f - p) / s;
  ofs[n]   = (1.0f - p) * 1e-20f;
}

// ---------------- kernel 4a: normalize from bf16 exp -> f32 out ----------------
__global__ __launch_bounds__(256) void norm_bf16_kernel(
    const u16* __restrict__ ebf, float* __restrict__ out,
    const float* __restrict__ scale, const float* __restrict__ ofs)
{
  const int total8 = NROWS * VOCAB / 8;     // VOCAB/8 = 4000
  const int stride = gridDim.x * blockDim.x;
  for (int i = blockIdx.x * 256 + threadIdx.x; i < total8; i += stride) {
    const int n = i / (VOCAB / 8);
    ushort4 v0 = ((const ushort4*)ebf)[i * 2];
    ushort4 v1 = ((const ushort4*)ebf)[i * 2 + 1];
    const float sc = scale[n], of = ofs[n];
    float4 o0, o1;
    o0.x = bf2f(v0.x) * sc + of; o0.y = bf2f(v0.y) * sc + of;
    o0.z = bf2f(v0.z) * sc + of; o0.w = bf2f(v0.w) * sc + of;
    o1.x = bf2f(v1.x) * sc + of; o1.y = bf2f(v1.y) * sc + of;
    o1.z = bf2f(v1.z) * sc + of; o1.w = bf2f(v1.w) * sc + of;
    ((float4*)out)[i * 2]     = o0;
    ((float4*)out)[i * 2 + 1] = o1;
  }
}

// ---------------- kernel 4b: normalize f32 in place (fallback) ----------------
__global__ __launch_bounds__(256) void norm_kernel(
    float* __restrict__ out, const float* __restrict__ scale,
    const float* __restrict__ ofs)
{
  const int total4 = NROWS * VOCAB / 4;
  const int stride = gridDim.x * blockDim.x;
  for (int i = blockIdx.x * 256 + threadIdx.x; i < total4; i += stride) {
    const int n = i / (VOCAB / 4);
    float4* p = (float4*)out + i;
    float4 v = *p;
    const float sc = scale[n], of = ofs[n];
    v.x = v.x * sc + of;
    v.y = v.y * sc + of;
    v.z = v.z * sc + of;
    v.w = v.w * sc + of;
    *p = v;
  }
}

// ---------------- kernel 5: scatter-add copy mass ----------------
__global__ __launch_bounds__(256) void scatter_kernel(
    float* __restrict__ out, const float* __restrict__ attn,
    const int* __restrict__ src, const float* __restrict__ pcopy)
{
  const int t = blockIdx.x * 256 + threadIdx.x;   // 65536 total
  const int n = t >> 6;
  const int s = t & 63;
  const int b = n & (BATCH - 1);
  const int v = src[s * BATCH + b];
  const float w = pcopy[n] * attn[(size_t)n * SLEN + s];
  atomicAdd(out + (size_t)n * VOCAB + v, w);
}

extern "C" void kernel_launch(void* const* d_in, const int* in_sizes, int n_in,
                              void* d_out, int out_size, void* d_ws, size_t ws_size,
                              hipStream_t stream) {
  const float* hidden = (const float*)d_in[0];
  const float* attn   = (const float*)d_in[1];
  const int*   src    = (const int*)d_in[2];
  const float* W      = (const float*)d_in[3];
  const float* w_copy = (const float*)d_in[4];
  const float* b_copy = (const float*)d_in[5];
  float* out = (float*)d_out;

  char* ws = (char*)d_ws;
  u16*   hbf     = (u16*)ws;                                   //  2,097,152 B
  float* pcopy   = (float*)(ws + 2097152);                     //      4,096 B
  float* partial = (float*)(ws + 2101248);                     //  1,024,000 B
  float* scale   = (float*)(ws + 3125248);                     //      4,096 B
  float* ofs     = (float*)(ws + 3129344);                     //      4,096 B
  u16*   ebf     = (u16*)(ws + 3133440);                       // 65,536,000 B
  const size_t need_bf16 = 3133440ull + 65536000ull;
  const int use_bf16 = (ws_size >= need_bf16) ? 1 : 0;

  prep_kernel<<<NROWS, 256, 0, stream>>>(hidden, w_copy, b_copy, hbf, pcopy);
  gemm_exp_kernel<<<8 * NBN, 256, 0, stream>>>(hbf, W, out, ebf, partial, use_bf16);
  rowsum_kernel<<<(NROWS + 255) / 256, 256, 0, stream>>>(partial, pcopy, scale, ofs);
  if (use_bf16)
    norm_bf16_kernel<<<2048, 256, 0, stream>>>(ebf, out, scale, ofs);
  else
    norm_kernel<<<2048, 256, 0, stream>>>(out, scale, ofs);
  scatter_kernel<<<NROWS * SLEN / 256, 256, 0, stream>>>(out, attn, src, pcopy);
}

// Round 10
// 193.310 us; speedup vs baseline: 1.2578x; 1.2578x over previous
//
#include <hip/hip_runtime.h>
#include <stdint.h>

typedef unsigned short u16;
typedef unsigned int u32;

#define NROWS 1024
#define DDIM  1024
#define SLEN  64
#define BATCH 64
#define VOCAB 32000
#define NBN   250            // 128-wide column blocks
#define PAD_WORD 1

typedef __attribute__((ext_vector_type(4))) float f32x4;
typedef __attribute__((ext_vector_type(8))) short s16x8;

__device__ __forceinline__ u16 f2bf(float x) {
  union { float f; u32 u; } v; v.f = x;
  u32 r = v.u + 0x7FFF + ((v.u >> 16) & 1);   // RNE
  return (u16)(r >> 16);
}
__device__ __forceinline__ float bf2f(u16 x) {
  union { u32 u; float f; } v; v.u = ((u32)x) << 16;
  return v.f;
}
// packed f32 pair -> bf16x2 in one instruction (RNE)
__device__ __forceinline__ u32 cvtpk(float a, float b) {
  u32 r;
  asm volatile("v_cvt_pk_bf16_f32 %0, %1, %2" : "=v"(r) : "v"(a), "v"(b));
  return r;
}

// ---------------- kernel 1: p_copy + hidden -> bf16 ----------------
__global__ __launch_bounds__(256) void prep_kernel(
    const float* __restrict__ hidden, const float* __restrict__ w_copy,
    const float* __restrict__ b_copy, u16* __restrict__ hbf,
    float* __restrict__ pcopy)
{
  const int n = blockIdx.x;
  const int tid = threadIdx.x;
  float4 h = ((const float4*)(hidden + (size_t)n * DDIM))[tid];
  float4 w = ((const float4*)w_copy)[tid];
  ushort4 hb;
  hb.x = f2bf(h.x); hb.y = f2bf(h.y); hb.z = f2bf(h.z); hb.w = f2bf(h.w);
  ((ushort4*)(hbf + (size_t)n * DDIM))[tid] = hb;
  float d = h.x * w.x + h.y * w.y + h.z * w.z + h.w * w.w;
  #pragma unroll
  for (int m = 1; m < 64; m <<= 1) d += __shfl_xor(d, m);
  __shared__ float ws4[4];
  if ((tid & 63) == 0) ws4[tid >> 6] = d;
  __syncthreads();
  if (tid == 0) {
    float s = ws4[0] + ws4[1] + ws4[2] + ws4[3] + b_copy[0];
    pcopy[n] = 1.0f / (1.0f + __expf(-s));
  }
}

// -------- kernel 2: 128x128 bf16 GEMM, 4 waves, BK=64, 2 blocks/CU.
//          B read as f32 W, COALESCED 4-lanes-per-row (256B contiguous per
//          4 lanes), reg-staged + v_cvt_pk; A via global_load_lds.
//          1 barrier / K-tile, counted waits. exp epilogue. ----
__global__ __launch_bounds__(256, 2) void gemm_exp_kernel(
    const u16* __restrict__ A, const float* __restrict__ Wf,
    float* __restrict__ out, u16* __restrict__ ebf,
    float* __restrict__ partial, const int use_bf16)
{
  __shared__ u16 lAs[2][8192];     // 128 rows x 64 cols bf16, XOR-swizzled slots
  __shared__ u16 lBs[2][8192];
  __shared__ float rowacc[2][128];

  const int tid  = threadIdx.x;
  const int lane = tid & 63;
  const int wid  = tid >> 6;        // 0..3
  const int wm   = wid >> 1;        // 0..1 (M)
  const int wn   = wid & 1;         // 0..1 (N)
  const int al   = lane & 15;
  const int ks   = lane >> 4;       // 0..3

  // XCD-chunked swizzle, 2000 blocks (2000 % 8 == 0 -> bijective).
  // 8 consecutive swz share bn -> same XCD -> B panel L2 reuse.
  const int orig = blockIdx.x;
  const int swz  = (orig & 7) * 250 + (orig >> 3);
  const int bm   = swz & 7;         // 8 M-blocks of 128
  const int bn   = swz >> 3;        // 250 N-blocks of 128

  const u16* Abase = A + (size_t)(bm * 128) * DDIM;

  // ---- A staging: 4 gload_lds/thread; linear dest, pre-swizzled source ----
  int arow_s[4], acs_s[4], asl_s[4];
  #pragma unroll
  for (int i = 0; i < 4; ++i) {
    const int s = (i * 4 + wid) * 64 + lane;   // 16B slot 0..1023
    asl_s[i]  = s;
    arow_s[i] = s >> 3;                        // 8 slots (128B) per row
    acs_s[i]  = (s & 7) ^ ((s >> 3) & 7);      // source slot, pre-swizzled
  }
#define STAGE_A(lptr, kt) do { \
    _Pragma("unroll") \
    for (int i_ = 0; i_ < 4; ++i_) \
      __builtin_amdgcn_global_load_lds( \
        (const __attribute__((address_space(1))) u32*)(Abase + (size_t)arow_s[i_] * DDIM + (kt) + acs_s[i_] * 8), \
        (__attribute__((address_space(3))) u32*)((lptr) + asl_s[i_] * 8), 16, 0, 0); \
  } while (0)

  // ---- B reg-staging, COALESCED: 4 threads per row, 16 f32 each;
  //      two row-groups (row, row+64) -> br[0..3], br[4..7] ----
  const int brow = tid >> 2;            // 0..63
  const int bq   = tid & 3;             // 16-f32 quarter within the 64-col row
  const float* Bsrc0 = Wf + (size_t)(bn * 128 + brow) * DDIM + bq * 16;
  const float* Bsrc1 = Bsrc0 + (size_t)64 * DDIM;
  f32x4 br[8];
#define ISSUE_B(kt) do { \
    br[0] = *(const f32x4*)(Bsrc0 + (kt));      \
    br[1] = *(const f32x4*)(Bsrc0 + (kt) + 4);  \
    br[2] = *(const f32x4*)(Bsrc0 + (kt) + 8);  \
    br[3] = *(const f32x4*)(Bsrc0 + (kt) + 12); \
    br[4] = *(const f32x4*)(Bsrc1 + (kt));      \
    br[5] = *(const f32x4*)(Bsrc1 + (kt) + 4);  \
    br[6] = *(const f32x4*)(Bsrc1 + (kt) + 8);  \
    br[7] = *(const f32x4*)(Bsrc1 + (kt) + 12); \
  } while (0)

  union pk8 { u32 w[4]; s16x8 v; };
#define CVT_WRITE_B(dst) do { \
    _Pragma("unroll") \
    for (int h_ = 0; h_ < 2; ++h_) { \
      const int r_ = brow + h_ * 64; \
      _Pragma("unroll") \
      for (int j_ = 0; j_ < 2; ++j_) { \
        pk8 p_; \
        f32x4 f0_ = br[h_ * 4 + j_ * 2], f1_ = br[h_ * 4 + j_ * 2 + 1]; \
        p_.w[0] = cvtpk(f0_.x, f0_.y); p_.w[1] = cvtpk(f0_.z, f0_.w); \
        p_.w[2] = cvtpk(f1_.x, f1_.y); p_.w[3] = cvtpk(f1_.z, f1_.w); \
        const int sl_ = (bq * 2 + j_) ^ (r_ & 7); \
        *(s16x8*)((dst) + r_ * 64 + sl_ * 8) = p_.v; \
      } \
    } } while (0)

#define WL(n) do { asm volatile("s_waitcnt lgkmcnt(" #n ")" ::: "memory"); \
                   __builtin_amdgcn_sched_barrier(0); } while (0)
#define WV(n) do { asm volatile("s_waitcnt vmcnt(" #n ")" ::: "memory"); \
                   __builtin_amdgcn_sched_barrier(0); } while (0)
#define BAR() do { __builtin_amdgcn_sched_barrier(0); \
                   __builtin_amdgcn_s_barrier(); \
                   __builtin_amdgcn_sched_barrier(0); } while (0)

#define RD_A(buf) do { \
    _Pragma("unroll") \
    for (int mi = 0; mi < 4; ++mi) { \
      const int r_ = wm * 64 + mi * 16 + al; \
      const u16* p_ = (buf) + r_ * 64; \
      af[mi][0] = *(const s16x8*)(p_ + ((ks)     ^ (r_ & 7)) * 8); \
      af[mi][1] = *(const s16x8*)(p_ + ((4 + ks) ^ (r_ & 7)) * 8); \
    } } while (0)
#define RD_BLO(buf) do { \
    _Pragma("unroll") \
    for (int ni = 0; ni < 2; ++ni) { \
      const int r_ = wn * 64 + ni * 16 + al; \
      const u16* p_ = (buf) + r_ * 64; \
      bl[ni][0] = *(const s16x8*)(p_ + ((ks)     ^ (r_ & 7)) * 8); \
      bl[ni][1] = *(const s16x8*)(p_ + ((4 + ks) ^ (r_ & 7)) * 8); \
    } } while (0)
#define RD_BHI(buf) do { \
    _Pragma("unroll") \
    for (int ni = 0; ni < 2; ++ni) { \
      const int r_ = wn * 64 + 32 + ni * 16 + al; \
      const u16* p_ = (buf) + r_ * 64; \
      bh[ni][0] = *(const s16x8*)(p_ + ((ks)     ^ (r_ & 7)) * 8); \
      bh[ni][1] = *(const s16x8*)(p_ + ((4 + ks) ^ (r_ & 7)) * 8); \
    } } while (0)
#define MM(BF, c0) do { \
    __builtin_amdgcn_s_setprio(1); \
    _Pragma("unroll") \
    for (int mi = 0; mi < 4; ++mi) \
      _Pragma("unroll") \
      for (int ni = 0; ni < 2; ++ni) \
        _Pragma("unroll") \
        for (int kk = 0; kk < 2; ++kk) \
          acc[mi][(c0) + ni] = __builtin_amdgcn_mfma_f32_16x16x32_bf16( \
              af[mi][kk], BF[ni][kk], acc[mi][(c0) + ni], 0, 0, 0); \
    __builtin_amdgcn_s_setprio(0); \
  } while (0)

  u16* lAc = &lAs[0][0]; u16* lBc = &lBs[0][0];
  u16* lAn = &lAs[1][0]; u16* lBn = &lBs[1][0];

  // ---- prologue ----
  ISSUE_B(0);                 // vm: [B0 x8]
  STAGE_A(lAc, 0);            // vm: [B0 x8, A0 x4]
  WV(4);                      // B0 regs landed (A0 flying)
  CVT_WRITE_B(lBc);
  ISSUE_B(64);                // vm: [A0 x4, B1 x8]
  WL(0);                      // ds_writes drained
  WV(8);                      // A0 landed (B1 remains)
  BAR();

  f32x4 acc[4][4];
  #pragma unroll
  for (int i = 0; i < 4; ++i)
    #pragma unroll
    for (int j = 0; j < 4; ++j)
      acc[i][j] = (f32x4){0.f, 0.f, 0.f, 0.f};

  s16x8 af[4][2], bl[2][2], bh[2][2];

  for (int t = 0; t < 15; ++t) {
    // entry invariant: vm = [B(t+1) x8]; lgkm empty; cur buffers ready
    RD_A(lAc); RD_BLO(lBc);                 // 12 ds_reads
    STAGE_A(lAn, (t + 1) * 64);             // vm: [B(t+1) 8, A(t+1) 4]
    WL(4);                                  // af+bl retired
    MM(bl, 0);                              // 16 MFMA (B(t+1) gains cover)
    WV(4);                                  // B(t+1) regs landed (A flying)
    CVT_WRITE_B(lBn);                       // 4 ds_writes into next buf
    if (t < 14) ISSUE_B((t + 2) * 64);      // vm: [A(t+1) 4, B(t+2) 8]
    RD_BHI(lBc);                            // lgkm: 4 wr + 4 rd
    WL(0);                                  // bhi ready, writes drained
    MM(bh, 2);
    if (t < 14) { WV(8); } else { WV(0); }  // A(t+1) landed (B(t+2) flies)
    BAR();                                  // next buffers ready for all waves
    u16* tp = lAc; lAc = lAn; lAn = tp;
    tp = lBc; lBc = lBn; lBn = tp;
  }
  // ---- final tile t=15 ----
  RD_A(lAc); RD_BLO(lBc);
  WL(0);
  MM(bl, 0);
  RD_BHI(lBc);
  WL(0);
  MM(bh, 2);

#undef STAGE_A
#undef ISSUE_B
#undef CVT_WRITE_B
#undef WL
#undef WV
#undef BAR

  // ---- epilogue: e = exp(logit), write (bf16 or f32), row-sums ----
  const int g = ks;                 // C/D: row = g*4 + j, col = lane&15
  float rsum[4][4];
  #pragma unroll
  for (int mi = 0; mi < 4; ++mi)
    #pragma unroll
    for (int j = 0; j < 4; ++j) rsum[mi][j] = 0.f;

  const size_t grow0 = (size_t)(bm * 128 + wm * 64);
  const int gcol0 = bn * 128 + wn * 64;
  #pragma unroll
  for (int mi = 0; mi < 4; ++mi) {
    #pragma unroll
    for (int j = 0; j < 4; ++j) {
      const size_t row = grow0 + mi * 16 + g * 4 + j;
      #pragma unroll
      for (int ni = 0; ni < 4; ++ni) {
        const int col = gcol0 + ni * 16 + al;
        float e = __expf(acc[mi][ni][j]);
        if (col == PAD_WORD) e = 0.f;
        rsum[mi][j] += e;
        if (use_bf16) ebf[row * VOCAB + col] = f2bf(e);
        else          out[row * VOCAB + col] = e;
      }
    }
  }
  #pragma unroll
  for (int mi = 0; mi < 4; ++mi)
    #pragma unroll
    for (int j = 0; j < 4; ++j) {
      float v = rsum[mi][j];
      v += __shfl_xor(v, 1);
      v += __shfl_xor(v, 2);
      v += __shfl_xor(v, 4);
      v += __shfl_xor(v, 8);
      rsum[mi][j] = v;
    }
  if (al == 0) {
    #pragma unroll
    for (int mi = 0; mi < 4; ++mi)
      #pragma unroll
      for (int j = 0; j < 4; ++j)
        rowacc[wn][wm * 64 + mi * 16 + g * 4 + j] = rsum[mi][j];
  }
  __syncthreads();
  if (tid < 128)
    partial[(size_t)bn * NROWS + bm * 128 + tid] =
        rowacc[0][tid] + rowacc[1][tid];
}

// ---------------- kernel 3: reduce partials -> scale/ofs ----------------
__global__ __launch_bounds__(256) void rowsum_kernel(
    const float* __restrict__ partial, const float* __restrict__ pcopy,
    float* __restrict__ scale, float* __restrict__ ofs)
{
  const int n = blockIdx.x * 256 + threadIdx.x;
  if (n >= NROWS) return;
  float s = 0.f;
  for (int j = 0; j < NBN; ++j) s += partial[(size_t)j * NROWS + n];
  const float p = pcopy[n];
  scale[n] = (1.0f - p) / s;
  ofs[n]   = (1.0f - p) * 1e-20f;
}

// ---------------- kernel 4a: normalize from bf16 exp -> f32 out ----------------
__global__ __launch_bounds__(256) void norm_bf16_kernel(
    const u16* __restrict__ ebf, float* __restrict__ out,
    const float* __restrict__ scale, const float* __restrict__ ofs)
{
  const int total8 = NROWS * VOCAB / 8;     // VOCAB/8 = 4000
  const int stride = gridDim.x * blockDim.x;
  for (int i = blockIdx.x * 256 + threadIdx.x; i < total8; i += stride) {
    const int n = i / (VOCAB / 8);
    ushort4 v0 = ((const ushort4*)ebf)[i * 2];
    ushort4 v1 = ((const ushort4*)ebf)[i * 2 + 1];
    const float sc = scale[n], of = ofs[n];
    float4 o0, o1;
    o0.x = bf2f(v0.x) * sc + of; o0.y = bf2f(v0.y) * sc + of;
    o0.z = bf2f(v0.z) * sc + of; o0.w = bf2f(v0.w) * sc + of;
    o1.x = bf2f(v1.x) * sc + of; o1.y = bf2f(v1.y) * sc + of;
    o1.z = bf2f(v1.z) * sc + of; o1.w = bf2f(v1.w) * sc + of;
    ((float4*)out)[i * 2]     = o0;
    ((float4*)out)[i * 2 + 1] = o1;
  }
}

// ---------------- kernel 4b: normalize f32 in place (fallback) ----------------
__global__ __launch_bounds__(256) void norm_kernel(
    float* __restrict__ out, const float* __restrict__ scale,
    const float* __restrict__ ofs)
{
  const int total4 = NROWS * VOCAB / 4;
  const int stride = gridDim.x * blockDim.x;
  for (int i = blockIdx.x * 256 + threadIdx.x; i < total4; i += stride) {
    const int n = i / (VOCAB / 4);
    float4* p = (float4*)out + i;
    float4 v = *p;
    const float sc = scale[n], of = ofs[n];
    v.x = v.x * sc + of;
    v.y = v.y * sc + of;
    v.z = v.z * sc + of;
    v.w = v.w * sc + of;
    *p = v;
  }
}

// ---------------- kernel 5: scatter-add copy mass ----------------
__global__ __launch_bounds__(256) void scatter_kernel(
    float* __restrict__ out, const float* __restrict__ attn,
    const int* __restrict__ src, const float* __restrict__ pcopy)
{
  const int t = blockIdx.x * 256 + threadIdx.x;   // 65536 total
  const int n = t >> 6;
  const int s = t & 63;
  const int b = n & (BATCH - 1);
  const int v = src[s * BATCH + b];
  const float w = pcopy[n] * attn[(size_t)n * SLEN + s];
  atomicAdd(out + (size_t)n * VOCAB + v, w);
}

extern "C" void kernel_launch(void* const* d_in, const int* in_sizes, int n_in,
                              void* d_out, int out_size, void* d_ws, size_t ws_size,
                              hipStream_t stream) {
  const float* hidden = (const float*)d_in[0];
  const float* attn   = (const float*)d_in[1];
  const int*   src    = (const int*)d_in[2];
  const float* W      = (const float*)d_in[3];
  const float* w_copy = (const float*)d_in[4];
  const float* b_copy = (const float*)d_in[5];
  float* out = (float*)d_out;

  char* ws = (char*)d_ws;
  u16*   hbf     = (u16*)ws;                                   //  2,097,152 B
  float* pcopy   = (float*)(ws + 2097152);                     //      4,096 B
  float* partial = (float*)(ws + 2101248);                     //  1,024,000 B
  float* scale   = (float*)(ws + 3125248);                     //      4,096 B
  float* ofs     = (float*)(ws + 3129344);                     //      4,096 B
  u16*   ebf     = (u16*)(ws + 3133440);                       // 65,536,000 B
  const size_t need_bf16 = 3133440ull + 65536000ull;
  const int use_bf16 = (ws_size >= need_bf16) ? 1 : 0;

  prep_kernel<<<NROWS, 256, 0, stream>>>(hidden, w_copy, b_copy, hbf, pcopy);
  gemm_exp_kernel<<<8 * NBN, 256, 0, stream>>>(hbf, W, out, ebf, partial, use_bf16);
  rowsum_kernel<<<(NROWS + 255) / 256, 256, 0, stream>>>(partial, pcopy, scale, ofs);
  if (use_bf16)
    norm_bf16_kernel<<<2048, 256, 0, stream>>>(ebf, out, scale, ofs);
  else
    norm_kernel<<<2048, 256, 0, stream>>>(out, scale, ofs);
  scatter_kernel<<<NROWS * SLEN / 256, 256, 0, stream>>>(out, attn, src, pcopy);
}

// Round 11
// 171.147 us; speedup vs baseline: 1.4206x; 1.1295x over previous
//
#include <hip/hip_runtime.h>
#include <stdint.h>

typedef unsigned char  u8;
typedef unsigned short u16;
typedef unsigned int u32;

#define NROWS 1024
#define DDIM  1024
#define SLEN  64
#define BATCH 64
#define VOCAB 32000
#define NBN2  125            // 256-wide column blocks
#define PAD_WORD 1

typedef __attribute__((ext_vector_type(4))) float f32x4;

__device__ __forceinline__ u16 f2bf(float x) {
  union { float f; u32 u; } v; v.f = x;
  u32 r = v.u + 0x7FFF + ((v.u >> 16) & 1);   // RNE
  return (u16)(r >> 16);
}
__device__ __forceinline__ float bf2f(u16 x) {
  union { u32 u; float f; } v; v.u = ((u32)x) << 16;
  return v.f;
}
// f32 -> OCP e4m3fn, RNE. Valid for |x| < 448, no NaN inputs.
__device__ __forceinline__ u32 f2e4m3(float x) {
  union { float f; u32 u; } v; v.f = x;
  const u32 s = (v.u >> 31) << 7;
  const u32 m = v.u & 0x7FFFFFFFu;
  if (m < 0x3C800000u) {                 // |x| < 2^-6: subnormal (q in 0..8)
    union { u32 u; float f; } a; a.u = m;
    int q = (int)rintf(a.f * 512.0f);    // RNE; q==8 rolls into first normal
    return s | (u32)q;
  }
  u32 u2 = m + 0x7FFFFu + ((m >> 20) & 1);   // RNE on 20 dropped bits
  u32 code = (((u2 >> 23) - 120u) << 3) | ((u2 >> 20) & 7u);
  if (code > 0x7Eu) code = 0x7Eu;            // clamp to 448 (0x7F is NaN)
  return s | code;
}

// ---------------- kernel 1: p_copy + hidden -> fp8 ----------------
__global__ __launch_bounds__(256) void prep_kernel(
    const float* __restrict__ hidden, const float* __restrict__ w_copy,
    const float* __restrict__ b_copy, u8* __restrict__ hq,
    float* __restrict__ pcopy)
{
  const int n = blockIdx.x;
  const int tid = threadIdx.x;
  float4 h = ((const float4*)(hidden + (size_t)n * DDIM))[tid];
  float4 w = ((const float4*)w_copy)[tid];
  u32 q = f2e4m3(h.x) | (f2e4m3(h.y) << 8) | (f2e4m3(h.z) << 16) | (f2e4m3(h.w) << 24);
  ((u32*)(hq + (size_t)n * DDIM))[tid] = q;
  float d = h.x * w.x + h.y * w.y + h.z * w.z + h.w * w.w;
  #pragma unroll
  for (int m = 1; m < 64; m <<= 1) d += __shfl_xor(d, m);
  __shared__ float ws4[4];
  if ((tid & 63) == 0) ws4[tid >> 6] = d;
  __syncthreads();
  if (tid == 0) {
    float s = ws4[0] + ws4[1] + ws4[2] + ws4[3] + b_copy[0];
    pcopy[n] = 1.0f / (1.0f + __expf(-s));
  }
}

// ---------------- kernel 2: W -> fp8 ----------------
__global__ __launch_bounds__(256) void convw8_kernel(
    const float* __restrict__ W, u8* __restrict__ Wq)
{
  const int total = VOCAB * DDIM / 16;     // 2,048,000 chunks of 16 floats
  const int stride = gridDim.x * blockDim.x;
  for (int i = blockIdx.x * 256 + threadIdx.x; i < total; i += stride) {
    const f32x4* p = (const f32x4*)(W + (size_t)i * 16);
    f32x4 a = p[0], b = p[1], c = p[2], d = p[3];
    uint4 q;
    q.x = f2e4m3(a.x) | (f2e4m3(a.y) << 8) | (f2e4m3(a.z) << 16) | (f2e4m3(a.w) << 24);
    q.y = f2e4m3(b.x) | (f2e4m3(b.y) << 8) | (f2e4m3(b.z) << 16) | (f2e4m3(b.w) << 24);
    q.z = f2e4m3(c.x) | (f2e4m3(c.y) << 8) | (f2e4m3(c.z) << 16) | (f2e4m3(c.w) << 24);
    q.w = f2e4m3(d.x) | (f2e4m3(d.y) << 8) | (f2e4m3(d.z) << 16) | (f2e4m3(d.w) << 24);
    ((uint4*)Wq)[i] = q;
  }
}

// -------- kernel 3: 256x256 fp8 GEMM (B^T layout), BK=64, r4's 2-barrier
//          interleaved schedule with halved staging (fp8 = half the bytes).
//          Both operands via global_load_lds. exp epilogue -> bf16 + row sums.
//          LDS tile [256 rows][64 B], 16B-slot swizzle c' = c ^ (row&3) on
//          BOTH the gload_lds source and the ds_read address. ----
__global__ __launch_bounds__(512, 2) void gemm_exp_kernel(
    const u8* __restrict__ A, const u8* __restrict__ B,
    float* __restrict__ out, u16* __restrict__ ebf,
    float* __restrict__ partial, const int use_bf16)
{
  __shared__ u8 lA[2][16384];     // [dbuf][256 rows x 64 B]
  __shared__ u8 lB[2][16384];
  __shared__ float rowacc[4][256];

  const int tid  = threadIdx.x;
  const int lane = tid & 63;
  const int wid  = tid >> 6;        // 0..7
  const int wm   = wid >> 2;        // 0..1  (M)
  const int wn   = wid & 3;         // 0..3  (N)
  const int al   = lane & 15;
  const int ks   = lane >> 4;       // 0..3

  // bijective XCD-chunked swizzle for 500 blocks (q=62, r=4)
  const int orig = blockIdx.x;
  const int xcd  = orig & 7;
  const int idx  = orig >> 3;
  const int wg   = (xcd < 4 ? xcd * 63 : 252 + (xcd - 4) * 62) + idx;
  const int bm   = wg & 3;          // 4 M-blocks
  const int bn   = wg >> 2;         // 125 N-blocks

  const u8* Abase = A + (size_t)(bm * 256) * DDIM;
  const u8* Bbase = B + (size_t)(bn * 256) * DDIM;

  // staging: 1024 16B-slots/tile; thread covers slots sA and sA+512
  const int sA = wid * 64 + lane;        // 0..511
  const int rA = sA >> 2;                // row 0..127 (and +128 for 2nd load)
  const int cA = (lane & 3) ^ (rA & 3);  // pre-swizzled source slot

#define GLL(gp, lp) __builtin_amdgcn_global_load_lds( \
    (const __attribute__((address_space(1))) u32*)(gp), \
    (__attribute__((address_space(3))) u32*)(lp), 16, 0, 0)
#define STAGE_T(gbase, lptr, kt) do { \
    GLL((gbase) + (size_t)rA * DDIM + (kt) + cA * 16, (lptr) + sA * 16); \
    GLL((gbase) + (size_t)(rA + 128) * DDIM + (kt) + cA * 16, (lptr) + 8192 + sA * 16); \
  } while (0)

#define WL(n) do { asm volatile("s_waitcnt lgkmcnt(" #n ")" ::: "memory"); \
                   __builtin_amdgcn_sched_barrier(0); } while (0)
#define WV(n) do { asm volatile("s_waitcnt vmcnt(" #n ")" ::: "memory"); \
                   __builtin_amdgcn_sched_barrier(0); } while (0)
#define BAR() do { __builtin_amdgcn_sched_barrier(0); \
                   __builtin_amdgcn_s_barrier(); \
                   __builtin_amdgcn_sched_barrier(0); } while (0)

  // fragment reads: row r, k-half kk -> 8 bytes at logical unit kk*4+ks;
  // slot c_log = kk*2 + (ks>>1), phys = c_log ^ (r&3), half = ks&1
#define RD_ALO(buf) do { \
    _Pragma("unroll") \
    for (int mi = 0; mi < 4; ++mi) { \
      const int r_ = wm * 128 + mi * 16 + al; \
      const u8* p_ = (buf) + r_ * 64 + (ks & 1) * 8; \
      alo[mi][0] = *(const long*)(p_ + ((((ks >> 1))     ^ (r_ & 3)) * 16)); \
      alo[mi][1] = *(const long*)(p_ + ((((ks >> 1) + 2) ^ (r_ & 3)) * 16)); \
    } } while (0)
#define RD_AHI(buf) do { \
    _Pragma("unroll") \
    for (int mi = 0; mi < 4; ++mi) { \
      const int r_ = wm * 128 + 64 + mi * 16 + al; \
      const u8* p_ = (buf) + r_ * 64 + (ks & 1) * 8; \
      ahi[mi][0] = *(const long*)(p_ + ((((ks >> 1))     ^ (r_ & 3)) * 16)); \
      ahi[mi][1] = *(const long*)(p_ + ((((ks >> 1) + 2) ^ (r_ & 3)) * 16)); \
    } } while (0)
#define RD_B0(buf) do { \
    _Pragma("unroll") \
    for (int ni = 0; ni < 2; ++ni) { \
      const int r_ = wn * 64 + ni * 16 + al; \
      const u8* p_ = (buf) + r_ * 64 + (ks & 1) * 8; \
      b0f[ni][0] = *(const long*)(p_ + ((((ks >> 1))     ^ (r_ & 3)) * 16)); \
      b0f[ni][1] = *(const long*)(p_ + ((((ks >> 1) + 2) ^ (r_ & 3)) * 16)); \
    } } while (0)
#define RD_B1(buf) do { \
    _Pragma("unroll") \
    for (int ni = 0; ni < 2; ++ni) { \
      const int r_ = wn * 64 + 32 + ni * 16 + al; \
      const u8* p_ = (buf) + r_ * 64 + (ks & 1) * 8; \
      b1f[ni][0] = *(const long*)(p_ + ((((ks >> 1))     ^ (r_ & 3)) * 16)); \
      b1f[ni][1] = *(const long*)(p_ + ((((ks >> 1) + 2) ^ (r_ & 3)) * 16)); \
    } } while (0)
#define MM(AF, BF, r0, c0) do { \
    __builtin_amdgcn_s_setprio(1); \
    _Pragma("unroll") \
    for (int mi = 0; mi < 4; ++mi) \
      _Pragma("unroll") \
      for (int ni = 0; ni < 2; ++ni) \
        _Pragma("unroll") \
        for (int kk = 0; kk < 2; ++kk) \
          acc[(r0) + mi][(c0) + ni] = __builtin_amdgcn_mfma_f32_16x16x32_fp8_fp8( \
              AF[mi][kk], BF[ni][kk], acc[(r0) + mi][(c0) + ni], 0, 0, 0); \
    __builtin_amdgcn_s_setprio(0); \
  } while (0)

  u8* lAc = &lA[0][0]; u8* lBc = &lB[0][0];
  u8* lAn = &lA[1][0]; u8* lBn = &lB[1][0];

  f32x4 acc[8][4];
  #pragma unroll
  for (int i = 0; i < 8; ++i)
    #pragma unroll
    for (int j = 0; j < 4; ++j)
      acc[i][j] = (f32x4){0.f, 0.f, 0.f, 0.f};

  long alo[4][2], ahi[4][2], b0f[2][2], b1f[2][2];

  // ---- prologue: tile0 A+B, tile1 A ----
  STAGE_T(Abase, lAc, 0);       // vm 2
  STAGE_T(Bbase, lBc, 0);       // vm 4
  STAGE_T(Abase, lAn, 64);      // vm 6
  WV(2);                        // A0,B0 landed; A1 flying
  BAR();
  RD_ALO(lAc); RD_B0(lBc); RD_B1(lBc);   // 16 lgkm outstanding

  for (int t = 0; t < 15; ++t) {
    const int kt1 = (t + 1) * 64;
    const int kt2 = (t + 2) * 64;
    // entry: vm = [A(t+1) 2]; lgkm = 16 (alo 8, b0 4, b1 4)
    WL(4);                                  // alo+b0 ready (b1 flying)
    MM(alo, b0f, 0, 0);
    STAGE_T(Bbase, lBn, kt1);               // vm: [A(t+1) 2, B(t+1) 2]
    RD_AHI(lAc);                            // lgkm: b1 4 + ahi 8
    WL(8);                                  // b1 ready (ahi flying)
    MM(alo, b1f, 0, 2);
    WL(0);                                  // ahi ready; all cur reads retired
    MM(ahi, b0f, 4, 0);
    BAR();                                  // every wave done reading cur A
    if (t < 14) STAGE_T(Abase, lAc, kt2);   // overwrite cur A for t+2
    if (t < 14) { WV(2); } else { WV(0); }  // A(t+1)+B(t+1) landed
    BAR();                                  // next buffers visible to all
    RD_ALO(lAn); RD_B0(lBn);
    MM(ahi, b1f, 4, 2);                     // reg-only, overlaps fresh reads
    RD_B1(lBn);
    u8* tp = lAc; lAc = lAn; lAn = tp;
    tp = lBc; lBc = lBn; lBn = tp;
  }
  // ---- final tile t=15 (reads already issued at t=14 tail) ----
  WL(4);
  MM(alo, b0f, 0, 0);
  RD_AHI(lAc);
  WL(8);
  MM(alo, b1f, 0, 2);
  WL(0);
  MM(ahi, b0f, 4, 0);
  MM(ahi, b1f, 4, 2);

#undef GLL
#undef STAGE_T
#undef WL
#undef WV
#undef BAR

  // ---- epilogue: e = exp(logit), write (bf16 or f32), row-sums ----
  const int g = ks;                 // C/D: row = g*4 + j, col = lane&15
  float rsum[8][4];
  #pragma unroll
  for (int mi = 0; mi < 8; ++mi)
    #pragma unroll
    for (int j = 0; j < 4; ++j) rsum[mi][j] = 0.f;

  const size_t grow0 = (size_t)(bm * 256 + wm * 128);
  const int gcol0 = bn * 256 + wn * 64;
  #pragma unroll
  for (int mi = 0; mi < 8; ++mi) {
    const int rofs = (mi >> 2) * 64 + (mi & 3) * 16 + g * 4;
    #pragma unroll
    for (int j = 0; j < 4; ++j) {
      const size_t row = grow0 + rofs + j;
      #pragma unroll
      for (int ni = 0; ni < 4; ++ni) {
        const int col = gcol0 + (ni >> 1) * 32 + (ni & 1) * 16 + al;
        float e = __expf(acc[mi][ni][j]);
        if (col == PAD_WORD) e = 0.f;
        rsum[mi][j] += e;
        if (use_bf16) ebf[row * VOCAB + col] = f2bf(e);
        else          out[row * VOCAB + col] = e;
      }
    }
  }
  #pragma unroll
  for (int mi = 0; mi < 8; ++mi)
    #pragma unroll
    for (int j = 0; j < 4; ++j) {
      float v = rsum[mi][j];
      v += __shfl_xor(v, 1);
      v += __shfl_xor(v, 2);
      v += __shfl_xor(v, 4);
      v += __shfl_xor(v, 8);
      rsum[mi][j] = v;
    }
  if (al == 0) {
    #pragma unroll
    for (int mi = 0; mi < 8; ++mi)
      #pragma unroll
      for (int j = 0; j < 4; ++j)
        rowacc[wn][wm * 128 + (mi >> 2) * 64 + (mi & 3) * 16 + g * 4 + j] =
            rsum[mi][j];
  }
  __syncthreads();
  if (tid < 256)
    partial[(size_t)bn * NROWS + bm * 256 + tid] =
        rowacc[0][tid] + rowacc[1][tid] + rowacc[2][tid] + rowacc[3][tid];
}

// ---------------- kernel 4: reduce partials -> scale/ofs ----------------
__global__ __launch_bounds__(256) void rowsum_kernel(
    const float* __restrict__ partial, const float* __restrict__ pcopy,
    float* __restrict__ scale, float* __restrict__ ofs)
{
  const int n = blockIdx.x * 256 + threadIdx.x;
  if (n >= NROWS) return;
  float s = 0.f;
  for (int j = 0; j < NBN2; ++j) s += partial[(size_t)j * NROWS + n];
  const float p = pcopy[n];
  scale[n] = (1.0f - p) / s;
  ofs[n]   = (1.0f - p) * 1e-20f;
}

// ---------------- kernel 5a: normalize from bf16 exp -> f32 out ----------------
__global__ __launch_bounds__(256) void norm_bf16_kernel(
    const u16* __restrict__ ebf, float* __restrict__ out,
    const float* __restrict__ scale, const float* __restrict__ ofs)
{
  const int total8 = NROWS * VOCAB / 8;     // VOCAB/8 = 4000
  const int stride = gridDim.x * blockDim.x;
  for (int i = blockIdx.x * 256 + threadIdx.x; i < total8; i += stride) {
    const int n = i / (VOCAB / 8);
    ushort4 v0 = ((const ushort4*)ebf)[i * 2];
    ushort4 v1 = ((const ushort4*)ebf)[i * 2 + 1];
    const float sc = scale[n], of = ofs[n];
    float4 o0, o1;
    o0.x = bf2f(v0.x) * sc + of; o0.y = bf2f(v0.y) * sc + of;
    o0.z = bf2f(v0.z) * sc + of; o0.w = bf2f(v0.w) * sc + of;
    o1.x = bf2f(v1.x) * sc + of; o1.y = bf2f(v1.y) * sc + of;
    o1.z = bf2f(v1.z) * sc + of; o1.w = bf2f(v1.w) * sc + of;
    ((float4*)out)[i * 2]     = o0;
    ((float4*)out)[i * 2 + 1] = o1;
  }
}

// ---------------- kernel 5b: normalize f32 in place (fallback) ----------------
__global__ __launch_bounds__(256) void norm_kernel(
    float* __restrict__ out, const float* __restrict__ scale,
    const float* __restrict__ ofs)
{
  const int total4 = NROWS * VOCAB / 4;
  const int stride = gridDim.x * blockDim.x;
  for (int i = blockIdx.x * 256 + threadIdx.x; i < total4; i += stride) {
    const int n = i / (VOCAB / 4);
    float4* p = (float4*)out + i;
    float4 v = *p;
    const float sc = scale[n], of = ofs[n];
    v.x = v.x * sc + of;
    v.y = v.y * sc + of;
    v.z = v.z * sc + of;
    v.w = v.w * sc + of;
    *p = v;
  }
}

// ---------------- kernel 6: scatter-add copy mass ----------------
__global__ __launch_bounds__(256) void scatter_kernel(
    float* __restrict__ out, const float* __restrict__ attn,
    const int* __restrict__ src, const float* __restrict__ pcopy)
{
  const int t = blockIdx.x * 256 + threadIdx.x;   // 65536 total
  const int n = t >> 6;
  const int s = t & 63;
  const int b = n & (BATCH - 1);
  const int v = src[s * BATCH + b];
  const float w = pcopy[n] * attn[(size_t)n * SLEN + s];
  atomicAdd(out + (size_t)n * VOCAB + v, w);
}

extern "C" void kernel_launch(void* const* d_in, const int* in_sizes, int n_in,
                              void* d_out, int out_size, void* d_ws, size_t ws_size,
                              hipStream_t stream) {
  const float* hidden = (const float*)d_in[0];
  const float* attn   = (const float*)d_in[1];
  const int*   src    = (const int*)d_in[2];
  const float* W      = (const float*)d_in[3];
  const float* w_copy = (const float*)d_in[4];
  const float* b_copy = (const float*)d_in[5];
  float* out = (float*)d_out;

  char* ws = (char*)d_ws;
  u8*    Wq      = (u8*)ws;                                    // 32,768,000 B
  u8*    hq      = (u8*)(ws + 32768000);                       //  1,048,576 B
  float* pcopy   = (float*)(ws + 33816576);                    //      4,096 B
  float* partial = (float*)(ws + 33820672);                    //  1,024,000 B
  float* scale   = (float*)(ws + 34844672);                    //      4,096 B
  float* ofs     = (float*)(ws + 34848768);                    //      4,096 B
  u16*   ebf     = (u16*)(ws + 34852864);                      // 65,536,000 B
  const size_t need_bf16 = 34852864ull + 65536000ull;
  const int use_bf16 = (ws_size >= need_bf16) ? 1 : 0;

  prep_kernel<<<NROWS, 256, 0, stream>>>(hidden, w_copy, b_copy, hq, pcopy);
  convw8_kernel<<<2048, 256, 0, stream>>>(W, Wq);
  gemm_exp_kernel<<<4 * NBN2, 512, 0, stream>>>(hq, Wq, out, ebf, partial, use_bf16);
  rowsum_kernel<<<(NROWS + 255) / 256, 256, 0, stream>>>(partial, pcopy, scale, ofs);
  if (use_bf16)
    norm_bf16_kernel<<<2048, 256, 0, stream>>>(ebf, out, scale, ofs);
  else
    norm_kernel<<<2048, 256, 0, stream>>>(out, scale, ofs);
  scatter_kernel<<<NROWS * SLEN / 256, 256, 0, stream>>>(out, attn, src, pcopy);
}

// Round 12
// 160.013 us; speedup vs baseline: 1.5195x; 1.0696x over previous
//
#include <hip/hip_runtime.h>
#include <stdint.h>

typedef unsigned char  u8;
typedef unsigned short u16;
typedef unsigned int u32;

#define NROWS 1024
#define DDIM  1024
#define SLEN  64
#define BATCH 64
#define VOCAB 32000
#define NBN2  125            // 256-wide column blocks
#define PAD_WORD 1

typedef __attribute__((ext_vector_type(4))) float f32x4;
typedef __attribute__((ext_vector_type(2))) long i64x2;

__device__ __forceinline__ u16 f2bf(float x) {
  union { float f; u32 u; } v; v.f = x;
  u32 r = v.u + 0x7FFF + ((v.u >> 16) & 1);   // RNE
  return (u16)(r >> 16);
}
__device__ __forceinline__ float bf2f(u16 x) {
  union { u32 u; float f; } v; v.u = ((u32)x) << 16;
  return v.f;
}
// f32 -> OCP e4m3fn, RNE. Valid for |x| < 448, no NaN inputs.
__device__ __forceinline__ u32 f2e4m3(float x) {
  union { float f; u32 u; } v; v.f = x;
  const u32 s = (v.u >> 31) << 7;
  const u32 m = v.u & 0x7FFFFFFFu;
  if (m < 0x3C800000u) {                 // |x| < 2^-6: subnormal (q in 0..8)
    union { u32 u; float f; } a; a.u = m;
    int q = (int)rintf(a.f * 512.0f);    // RNE; q==8 rolls into first normal
    return s | (u32)q;
  }
  u32 u2 = m + 0x7FFFFu + ((m >> 20) & 1);   // RNE on 20 dropped bits
  u32 code = (((u2 >> 23) - 120u) << 3) | ((u2 >> 20) & 7u);
  if (code > 0x7Eu) code = 0x7Eu;            // clamp to 448 (0x7F is NaN)
  return s | code;
}
__device__ __forceinline__ u32 pk4e4m3(float4 f) {
  return f2e4m3(f.x) | (f2e4m3(f.y) << 8) | (f2e4m3(f.z) << 16) | (f2e4m3(f.w) << 24);
}

// K-interleaved fp8 layout, per 64-k block: 16B unit u holds
// k[8u..8u+8) || k[32+8u..32+8u+8).  (Same permutation for A and B ->
// MFMA dot products pair correctly.)

// ---------------- kernel 1: p_copy + hidden -> fp8 (interleaved) ----------------
__global__ __launch_bounds__(256) void prep_kernel(
    const float* __restrict__ hidden, const float* __restrict__ w_copy,
    const float* __restrict__ b_copy, u8* __restrict__ hq,
    float* __restrict__ pcopy)
{
  const int n = blockIdx.x;
  const int tid = threadIdx.x;
  float4 h = ((const float4*)(hidden + (size_t)n * DDIM))[tid];
  float4 w = ((const float4*)w_copy)[tid];
  const int kb   = tid * 4;
  const int blk  = kb >> 6;
  const int kk   = (kb >> 5) & 1;
  const int u    = (kb >> 3) & 3;
  const int off  = kb & 7;              // 0 or 4
  ((u32*)(hq + (size_t)n * DDIM + blk * 64 + u * 16 + kk * 8 + off))[0] = pk4e4m3(h);
  float d = h.x * w.x + h.y * w.y + h.z * w.z + h.w * w.w;
  #pragma unroll
  for (int m = 1; m < 64; m <<= 1) d += __shfl_xor(d, m);
  __shared__ float ws4[4];
  if ((tid & 63) == 0) ws4[tid >> 6] = d;
  __syncthreads();
  if (tid == 0) {
    float s = ws4[0] + ws4[1] + ws4[2] + ws4[3] + b_copy[0];
    pcopy[n] = 1.0f / (1.0f + __expf(-s));
  }
}

// ---------------- kernel 2: W -> fp8 (interleaved) ----------------
// One thread per 64-float block: 16 float4 reads, 4 uint4 interleaved stores.
__global__ __launch_bounds__(256) void convw8_kernel(
    const float* __restrict__ W, u8* __restrict__ Wq)
{
  const int i = blockIdx.x * 256 + threadIdx.x;   // 512,000 blocks of 64
  if (i >= VOCAB * DDIM / 64) return;
  const float4* p = (const float4*)(W + (size_t)i * 64);
  float4 f[16];
  #pragma unroll
  for (int j = 0; j < 16; ++j) f[j] = p[j];
  uint4* q = (uint4*)(Wq + (size_t)i * 64);
  #pragma unroll
  for (int u = 0; u < 4; ++u) {
    uint4 o;
    o.x = pk4e4m3(f[2 * u]);
    o.y = pk4e4m3(f[2 * u + 1]);
    o.z = pk4e4m3(f[8 + 2 * u]);
    o.w = pk4e4m3(f[8 + 2 * u + 1]);
    q[u] = o;
  }
}

// -------- kernel 3: 256x256 fp8 GEMM (B^T layout), BK=64, 2-barrier
//          interleaved K-loop. Both operands via global_load_lds into
//          [256 rows][64 B] tiles; K-interleaved units -> frag reads are
//          single ds_read_b128 (conflict-free with X(r)=(r>>1)&3 swizzle,
//          applied on BOTH gload_lds source and ds_read addr). ----
__global__ __launch_bounds__(512, 2) void gemm_exp_kernel(
    const u8* __restrict__ A, const u8* __restrict__ B,
    float* __restrict__ out, u16* __restrict__ ebf,
    float* __restrict__ partial, const int use_bf16)
{
  __shared__ u8 lA[2][16384];     // [dbuf][256 rows x 64 B]
  __shared__ u8 lB[2][16384];
  __shared__ float rowacc[4][256];

  const int tid  = threadIdx.x;
  const int lane = tid & 63;
  const int wid  = tid >> 6;        // 0..7
  const int wm   = wid >> 2;        // 0..1  (M)
  const int wn   = wid & 3;         // 0..3  (N)
  const int al   = lane & 15;
  const int ks   = lane >> 4;       // 0..3

  // bijective XCD-chunked swizzle for 500 blocks (q=62, r=4)
  const int orig = blockIdx.x;
  const int xcd  = orig & 7;
  const int idx  = orig >> 3;
  const int wg   = (xcd < 4 ? xcd * 63 : 252 + (xcd - 4) * 62) + idx;
  const int bm   = wg & 3;          // 4 M-blocks
  const int bn   = wg >> 2;         // 125 N-blocks

  const u8* Abase = A + (size_t)(bm * 256) * DDIM;
  const u8* Bbase = B + (size_t)(bn * 256) * DDIM;

  // staging: 1024 16B-units/tile; thread covers units sA and sA+512
  const int sA = wid * 64 + lane;             // 0..511
  const int rA = sA >> 2;                     // row 0..127 (and +128)
  const int cA = (lane & 3) ^ ((rA >> 1) & 3);  // pre-swizzled source unit

#define GLL(gp, lp) __builtin_amdgcn_global_load_lds( \
    (const __attribute__((address_space(1))) u32*)(gp), \
    (__attribute__((address_space(3))) u32*)(lp), 16, 0, 0)
#define STAGE_T(gbase, lptr, kt) do { \
    GLL((gbase) + (size_t)rA * DDIM + (kt) + cA * 16, (lptr) + sA * 16); \
    GLL((gbase) + (size_t)(rA + 128) * DDIM + (kt) + cA * 16, (lptr) + 8192 + sA * 16); \
  } while (0)

#define WL(n) do { asm volatile("s_waitcnt lgkmcnt(" #n ")" ::: "memory"); \
                   __builtin_amdgcn_sched_barrier(0); } while (0)
#define WV(n) do { asm volatile("s_waitcnt vmcnt(" #n ")" ::: "memory"); \
                   __builtin_amdgcn_sched_barrier(0); } while (0)
#define BAR() do { __builtin_amdgcn_sched_barrier(0); \
                   __builtin_amdgcn_s_barrier(); \
                   __builtin_amdgcn_sched_barrier(0); } while (0)

  // fragment read: one b128 at row r, phys unit ks ^ ((r>>1)&3) -> both kk halves
#define RD_FR(dst, buf, rbase, cnt) do { \
    _Pragma("unroll") \
    for (int i_ = 0; i_ < (cnt); ++i_) { \
      const int r_ = (rbase) + i_ * 16 + al; \
      i64x2 v_ = *(const i64x2*)((buf) + r_ * 64 + (ks ^ ((r_ >> 1) & 3)) * 16); \
      dst[i_][0] = v_.x; dst[i_][1] = v_.y; \
    } } while (0)

#define MM(AF, BF, r0, c0) do { \
    __builtin_amdgcn_s_setprio(1); \
    _Pragma("unroll") \
    for (int mi = 0; mi < 4; ++mi) \
      _Pragma("unroll") \
      for (int ni = 0; ni < 2; ++ni) \
        _Pragma("unroll") \
        for (int kk = 0; kk < 2; ++kk) \
          acc[(r0) + mi][(c0) + ni] = __builtin_amdgcn_mfma_f32_16x16x32_fp8_fp8( \
              AF[mi][kk], BF[ni][kk], acc[(r0) + mi][(c0) + ni], 0, 0, 0); \
    __builtin_amdgcn_s_setprio(0); \
  } while (0)

  u8* lAc = &lA[0][0]; u8* lBc = &lB[0][0];
  u8* lAn = &lA[1][0]; u8* lBn = &lB[1][0];

  f32x4 acc[8][4];
  #pragma unroll
  for (int i = 0; i < 8; ++i)
    #pragma unroll
    for (int j = 0; j < 4; ++j)
      acc[i][j] = (f32x4){0.f, 0.f, 0.f, 0.f};

  long alo[4][2], ahi[4][2], b0f[2][2], b1f[2][2];

  // ---- prologue: tile0 A+B, tile1 A ----
  STAGE_T(Abase, lAc, 0);       // vm 2
  STAGE_T(Bbase, lBc, 0);       // vm 4
  STAGE_T(Abase, lAn, 64);      // vm 6
  WV(2);                        // A0,B0 landed; A1 flying
  BAR();
  RD_FR(alo, lAc, wm * 128, 4);
  RD_FR(b0f, lBc, wn * 64, 2);
  RD_FR(b1f, lBc, wn * 64 + 32, 2);     // lgkm 8 outstanding

  for (int t = 0; t < 15; ++t) {
    const int kt1 = (t + 1) * 64;
    const int kt2 = (t + 2) * 64;
    // entry: vm = [A(t+1) 2]; lgkm = 8 (alo 4, b0 2, b1 2)
    WL(2);                                  // alo+b0 ready (b1 flying)
    MM(alo, b0f, 0, 0);
    STAGE_T(Bbase, lBn, kt1);               // vm: [A(t+1) 2, B(t+1) 2]
    RD_FR(ahi, lAc, wm * 128 + 64, 4);      // lgkm: b1 2 + ahi 4
    WL(4);                                  // b1 ready (ahi flying)
    MM(alo, b1f, 0, 2);
    WL(0);                                  // ahi ready; all cur reads retired
    MM(ahi, b0f, 4, 0);
    BAR();                                  // every wave done reading cur A
    if (t < 14) STAGE_T(Abase, lAc, kt2);   // overwrite cur A for t+2
    if (t < 14) { WV(2); } else { WV(0); }  // A(t+1)+B(t+1) landed
    BAR();                                  // next buffers visible to all
    RD_FR(alo, lAn, wm * 128, 4);
    RD_FR(b0f, lBn, wn * 64, 2);
    MM(ahi, b1f, 4, 2);                     // reg-only, overlaps fresh reads
    RD_FR(b1f, lBn, wn * 64 + 32, 2);
    u8* tp = lAc; lAc = lAn; lAn = tp;
    tp = lBc; lBc = lBn; lBn = tp;
  }
  // ---- final tile t=15 (reads already issued at t=14 tail) ----
  WL(2);
  MM(alo, b0f, 0, 0);
  RD_FR(ahi, lAc, wm * 128 + 64, 4);
  WL(4);
  MM(alo, b1f, 0, 2);
  WL(0);
  MM(ahi, b0f, 4, 0);
  MM(ahi, b1f, 4, 2);

#undef GLL
#undef STAGE_T
#undef WL
#undef WV
#undef BAR
#undef RD_FR

  // ---- epilogue: e = exp(logit), write (bf16 or f32), row-sums ----
  const int g = ks;                 // C/D: row = g*4 + j, col = lane&15
  float rsum[8][4];
  #pragma unroll
  for (int mi = 0; mi < 8; ++mi)
    #pragma unroll
    for (int j = 0; j < 4; ++j) rsum[mi][j] = 0.f;

  const size_t grow0 = (size_t)(bm * 256 + wm * 128);
  const int gcol0 = bn * 256 + wn * 64;
  #pragma unroll
  for (int mi = 0; mi < 8; ++mi) {
    const int rofs = (mi >> 2) * 64 + (mi & 3) * 16 + g * 4;
    #pragma unroll
    for (int j = 0; j < 4; ++j) {
      const size_t row = grow0 + rofs + j;
      #pragma unroll
      for (int ni = 0; ni < 4; ++ni) {
        const int col = gcol0 + (ni >> 1) * 32 + (ni & 1) * 16 + al;
        float e = __expf(acc[mi][ni][j]);
        if (col == PAD_WORD) e = 0.f;
        rsum[mi][j] += e;
        if (use_bf16) ebf[row * VOCAB + col] = f2bf(e);
        else          out[row * VOCAB + col] = e;
      }
    }
  }
  #pragma unroll
  for (int mi = 0; mi < 8; ++mi)
    #pragma unroll
    for (int j = 0; j < 4; ++j) {
      float v = rsum[mi][j];
      v += __shfl_xor(v, 1);
      v += __shfl_xor(v, 2);
      v += __shfl_xor(v, 4);
      v += __shfl_xor(v, 8);
      rsum[mi][j] = v;
    }
  if (al == 0) {
    #pragma unroll
    for (int mi = 0; mi < 8; ++mi)
      #pragma unroll
      for (int j = 0; j < 4; ++j)
        rowacc[wn][wm * 128 + (mi >> 2) * 64 + (mi & 3) * 16 + g * 4 + j] =
            rsum[mi][j];
  }
  __syncthreads();
  if (tid < 256)
    partial[(size_t)bn * NROWS + bm * 256 + tid] =
        rowacc[0][tid] + rowacc[1][tid] + rowacc[2][tid] + rowacc[3][tid];
}

// ---------------- kernel 4: reduce partials -> scale/ofs ----------------
__global__ __launch_bounds__(256) void rowsum_kernel(
    const float* __restrict__ partial, const float* __restrict__ pcopy,
    float* __restrict__ scale, float* __restrict__ ofs)
{
  const int n = blockIdx.x * 256 + threadIdx.x;
  if (n >= NROWS) return;
  float s = 0.f;
  for (int j = 0; j < NBN2; ++j) s += partial[(size_t)j * NROWS + n];
  const float p = pcopy[n];
  scale[n] = (1.0f - p) / s;
  ofs[n]   = (1.0f - p) * 1e-20f;
}

// ---------------- kernel 5a: normalize from bf16 exp -> f32 out ----------------
__global__ __launch_bounds__(256) void norm_bf16_kernel(
    const u16* __restrict__ ebf, float* __restrict__ out,
    const float* __restrict__ scale, const float* __restrict__ ofs)
{
  const int total8 = NROWS * VOCAB / 8;     // VOCAB/8 = 4000
  const int stride = gridDim.x * blockDim.x;
  for (int i = blockIdx.x * 256 + threadIdx.x; i < total8; i += stride) {
    const int n = i / (VOCAB / 8);
    ushort4 v0 = ((const ushort4*)ebf)[i * 2];
    ushort4 v1 = ((const ushort4*)ebf)[i * 2 + 1];
    const float sc = scale[n], of = ofs[n];
    float4 o0, o1;
    o0.x = bf2f(v0.x) * sc + of; o0.y = bf2f(v0.y) * sc + of;
    o0.z = bf2f(v0.z) * sc + of; o0.w = bf2f(v0.w) * sc + of;
    o1.x = bf2f(v1.x) * sc + of; o1.y = bf2f(v1.y) * sc + of;
    o1.z = bf2f(v1.z) * sc + of; o1.w = bf2f(v1.w) * sc + of;
    ((float4*)out)[i * 2]     = o0;
    ((float4*)out)[i * 2 + 1] = o1;
  }
}

// ---------------- kernel 5b: normalize f32 in place (fallback) ----------------
__global__ __launch_bounds__(256) void norm_kernel(
    float* __restrict__ out, const float* __restrict__ scale,
    const float* __restrict__ ofs)
{
  const int total4 = NROWS * VOCAB / 4;
  const int stride = gridDim.x * blockDim.x;
  for (int i = blockIdx.x * 256 + threadIdx.x; i < total4; i += stride) {
    const int n = i / (VOCAB / 4);
    float4* p = (float4*)out + i;
    float4 v = *p;
    const float sc = scale[n], of = ofs[n];
    v.x = v.x * sc + of;
    v.y = v.y * sc + of;
    v.z = v.z * sc + of;
    v.w = v.w * sc + of;
    *p = v;
  }
}

// ---------------- kernel 6: scatter-add copy mass ----------------
__global__ __launch_bounds__(256) void scatter_kernel(
    float* __restrict__ out, const float* __restrict__ attn,
    const int* __restrict__ src, const float* __restrict__ pcopy)
{
  const int t = blockIdx.x * 256 + threadIdx.x;   // 65536 total
  const int n = t >> 6;
  const int s = t & 63;
  const int b = n & (BATCH - 1);
  const int v = src[s * BATCH + b];
  const float w = pcopy[n] * attn[(size_t)n * SLEN + s];
  atomicAdd(out + (size_t)n * VOCAB + v, w);
}

extern "C" void kernel_launch(void* const* d_in, const int* in_sizes, int n_in,
                              void* d_out, int out_size, void* d_ws, size_t ws_size,
                              hipStream_t stream) {
  const float* hidden = (const float*)d_in[0];
  const float* attn   = (const float*)d_in[1];
  const int*   src    = (const int*)d_in[2];
  const float* W      = (const float*)d_in[3];
  const float* w_copy = (const float*)d_in[4];
  const float* b_copy = (const float*)d_in[5];
  float* out = (float*)d_out;

  char* ws = (char*)d_ws;
  u8*    Wq      = (u8*)ws;                                    // 32,768,000 B
  u8*    hq      = (u8*)(ws + 32768000);                       //  1,048,576 B
  float* pcopy   = (float*)(ws + 33816576);                    //      4,096 B
  float* partial = (float*)(ws + 33820672);                    //  1,024,000 B
  float* scale   = (float*)(ws + 34844672);                    //      4,096 B
  float* ofs     = (float*)(ws + 34848768);                    //      4,096 B
  u16*   ebf     = (u16*)(ws + 34852864);                      // 65,536,000 B
  const size_t need_bf16 = 34852864ull + 65536000ull;
  const int use_bf16 = (ws_size >= need_bf16) ? 1 : 0;

  prep_kernel<<<NROWS, 256, 0, stream>>>(hidden, w_copy, b_copy, hq, pcopy);
  convw8_kernel<<<VOCAB * DDIM / 64 / 256, 256, 0, stream>>>(W, Wq);
  gemm_exp_kernel<<<4 * NBN2, 512, 0, stream>>>(hq, Wq, out, ebf, partial, use_bf16);
  rowsum_kernel<<<(NROWS + 255) / 256, 256, 0, stream>>>(partial, pcopy, scale, ofs);
  if (use_bf16)
    norm_bf16_kernel<<<2048, 256, 0, stream>>>(ebf, out, scale, ofs);
  else
    norm_kernel<<<2048, 256, 0, stream>>>(out, scale, ofs);
  scatter_kernel<<<NROWS * SLEN / 256, 256, 0, stream>>>(out, attn, src, pcopy);
}

// Round 13
// 148.251 us; speedup vs baseline: 1.6400x; 1.0793x over previous
//
#include <hip/hip_runtime.h>
#include <stdint.h>

typedef unsigned char  u8;
typedef unsigned short u16;
typedef unsigned int u32;

#define NROWS 1024
#define DDIM  1024
#define SLEN  64
#define BATCH 64
#define VOCAB 32000
#define NBN2  125            // 256-wide column blocks
#define PAD_WORD 1

typedef __attribute__((ext_vector_type(4))) float f32x4;
typedef __attribute__((ext_vector_type(2))) long i64x2;

__device__ __forceinline__ u16 f2bf(float x) {
  union { float f; u32 u; } v; v.f = x;
  u32 r = v.u + 0x7FFF + ((v.u >> 16) & 1);   // RNE
  return (u16)(r >> 16);
}
__device__ __forceinline__ float bf2f(u16 x) {
  union { u32 u; float f; } v; v.u = ((u32)x) << 16;
  return v.f;
}
// f32 -> OCP e4m3fn, RNE. Valid for |x| < 448, no NaN inputs.
__device__ __forceinline__ u32 f2e4m3(float x) {
  union { float f; u32 u; } v; v.f = x;
  const u32 s = (v.u >> 31) << 7;
  const u32 m = v.u & 0x7FFFFFFFu;
  if (m < 0x3C800000u) {                 // |x| < 2^-6: subnormal (q in 0..8)
    union { u32 u; float f; } a; a.u = m;
    int q = (int)rintf(a.f * 512.0f);    // RNE; q==8 rolls into first normal
    return s | (u32)q;
  }
  u32 u2 = m + 0x7FFFFu + ((m >> 20) & 1);   // RNE on 20 dropped bits
  u32 code = (((u2 >> 23) - 120u) << 3) | ((u2 >> 20) & 7u);
  if (code > 0x7Eu) code = 0x7Eu;            // clamp to 448 (0x7F is NaN)
  return s | code;
}
__device__ __forceinline__ u32 pk4e4m3(float4 f) {
  return f2e4m3(f.x) | (f2e4m3(f.y) << 8) | (f2e4m3(f.z) << 16) | (f2e4m3(f.w) << 24);
}

// K-interleaved fp8 layout, per 64-k block: 16B unit u holds
// k[8u..8u+8) || k[32+8u..32+8u+8).  (Same permutation for A and B ->
// MFMA dot products pair correctly.)

// -------- kernel 1: fused {p_copy + hidden->fp8} and {W->fp8}, both
//          K-interleaved. convw part: one thread per output 16B unit ->
//          contiguous stores, 2x-touched 64B lines on loads (near-BW). ----
__global__ __launch_bounds__(256) void prep_convw_kernel(
    const float* __restrict__ hidden, const float* __restrict__ w_copy,
    const float* __restrict__ b_copy, u8* __restrict__ hq,
    float* __restrict__ pcopy, const float* __restrict__ W,
    u8* __restrict__ Wq)
{
  const int tid = threadIdx.x;
  if (blockIdx.x < NROWS) {
    // ---- prep: one row per block ----
    const int n = blockIdx.x;
    float4 h = ((const float4*)(hidden + (size_t)n * DDIM))[tid];
    float4 w = ((const float4*)w_copy)[tid];
    const int kb   = tid * 4;
    const int blk  = kb >> 6;
    const int kk   = (kb >> 5) & 1;
    const int u    = (kb >> 3) & 3;
    const int off  = kb & 7;              // 0 or 4
    ((u32*)(hq + (size_t)n * DDIM + blk * 64 + u * 16 + kk * 8 + off))[0] = pk4e4m3(h);
    float d = h.x * w.x + h.y * w.y + h.z * w.z + h.w * w.w;
    #pragma unroll
    for (int m = 1; m < 64; m <<= 1) d += __shfl_xor(d, m);
    __shared__ float ws4[4];
    if ((tid & 63) == 0) ws4[tid >> 6] = d;
    __syncthreads();
    if (tid == 0) {
      float s = ws4[0] + ws4[1] + ws4[2] + ws4[3] + b_copy[0];
      pcopy[n] = 1.0f / (1.0f + __expf(-s));
    }
    return;
  }
  // ---- convw: one thread per 16B output unit ----
  const int i = (blockIdx.x - NROWS) * 256 + tid;   // 0 .. 2,048,000-1
  if (i >= VOCAB * DDIM / 16) return;
  const int blk = i >> 2;
  const int u   = i & 3;
  const float4* src = (const float4*)(W + (size_t)blk * 64 + u * 8);
  float4 a0 = src[0];
  float4 a1 = src[1];
  float4 b0 = src[8];      // +32 floats
  float4 b1 = src[9];
  uint4 o;
  o.x = pk4e4m3(a0); o.y = pk4e4m3(a1);
  o.z = pk4e4m3(b0); o.w = pk4e4m3(b1);
  ((uint4*)Wq)[i] = o;
}

// -------- kernel 2: 256x256 fp8 GEMM (B^T layout), BK=64, 2-barrier
//          interleaved K-loop. Both operands via global_load_lds into
//          [256 rows][64 B] tiles; K-interleaved units -> frag reads are
//          single ds_read_b128 (conflict-free with X(r)=(r>>1)&3 swizzle,
//          applied on BOTH gload_lds source and ds_read addr). ----
__global__ __launch_bounds__(512, 2) void gemm_exp_kernel(
    const u8* __restrict__ A, const u8* __restrict__ B,
    float* __restrict__ out, u16* __restrict__ ebf,
    float* __restrict__ partial, const int use_bf16)
{
  __shared__ u8 lA[2][16384];     // [dbuf][256 rows x 64 B]
  __shared__ u8 lB[2][16384];
  __shared__ float rowacc[4][256];

  const int tid  = threadIdx.x;
  const int lane = tid & 63;
  const int wid  = tid >> 6;        // 0..7
  const int wm   = wid >> 2;        // 0..1  (M)
  const int wn   = wid & 3;         // 0..3  (N)
  const int al   = lane & 15;
  const int ks   = lane >> 4;       // 0..3

  // bijective XCD-chunked swizzle for 500 blocks (q=62, r=4)
  const int orig = blockIdx.x;
  const int xcd  = orig & 7;
  const int idx  = orig >> 3;
  const int wg   = (xcd < 4 ? xcd * 63 : 252 + (xcd - 4) * 62) + idx;
  const int bm   = wg & 3;          // 4 M-blocks
  const int bn   = wg >> 2;         // 125 N-blocks

  const u8* Abase = A + (size_t)(bm * 256) * DDIM;
  const u8* Bbase = B + (size_t)(bn * 256) * DDIM;

  // staging: 1024 16B-units/tile; thread covers units sA and sA+512
  const int sA = wid * 64 + lane;             // 0..511
  const int rA = sA >> 2;                     // row 0..127 (and +128)
  const int cA = (lane & 3) ^ ((rA >> 1) & 3);  // pre-swizzled source unit

#define GLL(gp, lp) __builtin_amdgcn_global_load_lds( \
    (const __attribute__((address_space(1))) u32*)(gp), \
    (__attribute__((address_space(3))) u32*)(lp), 16, 0, 0)
#define STAGE_T(gbase, lptr, kt) do { \
    GLL((gbase) + (size_t)rA * DDIM + (kt) + cA * 16, (lptr) + sA * 16); \
    GLL((gbase) + (size_t)(rA + 128) * DDIM + (kt) + cA * 16, (lptr) + 8192 + sA * 16); \
  } while (0)

#define WL(n) do { asm volatile("s_waitcnt lgkmcnt(" #n ")" ::: "memory"); \
                   __builtin_amdgcn_sched_barrier(0); } while (0)
#define WV(n) do { asm volatile("s_waitcnt vmcnt(" #n ")" ::: "memory"); \
                   __builtin_amdgcn_sched_barrier(0); } while (0)
#define BAR() do { __builtin_amdgcn_sched_barrier(0); \
                   __builtin_amdgcn_s_barrier(); \
                   __builtin_amdgcn_sched_barrier(0); } while (0)

  // fragment read: one b128 at row r, phys unit ks ^ ((r>>1)&3) -> both kk halves
#define RD_FR(dst, buf, rbase, cnt) do { \
    _Pragma("unroll") \
    for (int i_ = 0; i_ < (cnt); ++i_) { \
      const int r_ = (rbase) + i_ * 16 + al; \
      i64x2 v_ = *(const i64x2*)((buf) + r_ * 64 + (ks ^ ((r_ >> 1) & 3)) * 16); \
      dst[i_][0] = v_.x; dst[i_][1] = v_.y; \
    } } while (0)

#define MM(AF, BF, r0, c0) do { \
    __builtin_amdgcn_s_setprio(1); \
    _Pragma("unroll") \
    for (int mi = 0; mi < 4; ++mi) \
      _Pragma("unroll") \
      for (int ni = 0; ni < 2; ++ni) \
        _Pragma("unroll") \
        for (int kk = 0; kk < 2; ++kk) \
          acc[(r0) + mi][(c0) + ni] = __builtin_amdgcn_mfma_f32_16x16x32_fp8_fp8( \
              AF[mi][kk], BF[ni][kk], acc[(r0) + mi][(c0) + ni], 0, 0, 0); \
    __builtin_amdgcn_s_setprio(0); \
  } while (0)

  u8* lAc = &lA[0][0]; u8* lBc = &lB[0][0];
  u8* lAn = &lA[1][0]; u8* lBn = &lB[1][0];

  f32x4 acc[8][4];
  #pragma unroll
  for (int i = 0; i < 8; ++i)
    #pragma unroll
    for (int j = 0; j < 4; ++j)
      acc[i][j] = (f32x4){0.f, 0.f, 0.f, 0.f};

  long alo[4][2], ahi[4][2], b0f[2][2], b1f[2][2];

  // ---- prologue: tile0 A+B, tile1 A ----
  STAGE_T(Abase, lAc, 0);       // vm 2
  STAGE_T(Bbase, lBc, 0);       // vm 4
  STAGE_T(Abase, lAn, 64);      // vm 6
  WV(2);                        // A0,B0 landed; A1 flying
  BAR();
  RD_FR(alo, lAc, wm * 128, 4);
  RD_FR(b0f, lBc, wn * 64, 2);
  RD_FR(b1f, lBc, wn * 64 + 32, 2);     // lgkm 8 outstanding

  for (int t = 0; t < 15; ++t) {
    const int kt1 = (t + 1) * 64;
    const int kt2 = (t + 2) * 64;
    // entry: vm = [A(t+1) 2]; lgkm = 8 (alo 4, b0 2, b1 2)
    WL(2);                                  // alo+b0 ready (b1 flying)
    MM(alo, b0f, 0, 0);
    STAGE_T(Bbase, lBn, kt1);               // vm: [A(t+1) 2, B(t+1) 2]
    RD_FR(ahi, lAc, wm * 128 + 64, 4);      // lgkm: b1 2 + ahi 4
    WL(4);                                  // b1 ready (ahi flying)
    MM(alo, b1f, 0, 2);
    WL(0);                                  // ahi ready; all cur reads retired
    MM(ahi, b0f, 4, 0);
    BAR();                                  // every wave done reading cur A
    if (t < 14) STAGE_T(Abase, lAc, kt2);   // overwrite cur A for t+2
    if (t < 14) { WV(2); } else { WV(0); }  // A(t+1)+B(t+1) landed
    BAR();                                  // next buffers visible to all
    RD_FR(alo, lAn, wm * 128, 4);
    RD_FR(b0f, lBn, wn * 64, 2);
    MM(ahi, b1f, 4, 2);                     // reg-only, overlaps fresh reads
    RD_FR(b1f, lBn, wn * 64 + 32, 2);
    u8* tp = lAc; lAc = lAn; lAn = tp;
    tp = lBc; lBc = lBn; lBn = tp;
  }
  // ---- final tile t=15 (reads already issued at t=14 tail) ----
  WL(2);
  MM(alo, b0f, 0, 0);
  RD_FR(ahi, lAc, wm * 128 + 64, 4);
  WL(4);
  MM(alo, b1f, 0, 2);
  WL(0);
  MM(ahi, b0f, 4, 0);
  MM(ahi, b1f, 4, 2);

#undef GLL
#undef STAGE_T
#undef WL
#undef WV
#undef BAR
#undef RD_FR

  // ---- epilogue: e = exp(logit), write (bf16 or f32), row-sums ----
  const int g = ks;                 // C/D: row = g*4 + j, col = lane&15
  float rsum[8][4];
  #pragma unroll
  for (int mi = 0; mi < 8; ++mi)
    #pragma unroll
    for (int j = 0; j < 4; ++j) rsum[mi][j] = 0.f;

  const size_t grow0 = (size_t)(bm * 256 + wm * 128);
  const int gcol0 = bn * 256 + wn * 64;
  #pragma unroll
  for (int mi = 0; mi < 8; ++mi) {
    const int rofs = (mi >> 2) * 64 + (mi & 3) * 16 + g * 4;
    #pragma unroll
    for (int j = 0; j < 4; ++j) {
      const size_t row = grow0 + rofs + j;
      #pragma unroll
      for (int ni = 0; ni < 4; ++ni) {
        const int col = gcol0 + (ni >> 1) * 32 + (ni & 1) * 16 + al;
        float e = __expf(acc[mi][ni][j]);
        if (col == PAD_WORD) e = 0.f;
        rsum[mi][j] += e;
        if (use_bf16) ebf[row * VOCAB + col] = f2bf(e);
        else          out[row * VOCAB + col] = e;
      }
    }
  }
  #pragma unroll
  for (int mi = 0; mi < 8; ++mi)
    #pragma unroll
    for (int j = 0; j < 4; ++j) {
      float v = rsum[mi][j];
      v += __shfl_xor(v, 1);
      v += __shfl_xor(v, 2);
      v += __shfl_xor(v, 4);
      v += __shfl_xor(v, 8);
      rsum[mi][j] = v;
    }
  if (al == 0) {
    #pragma unroll
    for (int mi = 0; mi < 8; ++mi)
      #pragma unroll
      for (int j = 0; j < 4; ++j)
        rowacc[wn][wm * 128 + (mi >> 2) * 64 + (mi & 3) * 16 + g * 4 + j] =
            rsum[mi][j];
  }
  __syncthreads();
  if (tid < 256)
    partial[(size_t)bn * NROWS + bm * 256 + tid] =
        rowacc[0][tid] + rowacc[1][tid] + rowacc[2][tid] + rowacc[3][tid];
}

// ---------------- kernel 3: reduce partials -> scale/ofs ----------------
__global__ __launch_bounds__(256) void rowsum_kernel(
    const float* __restrict__ partial, const float* __restrict__ pcopy,
    float* __restrict__ scale, float* __restrict__ ofs)
{
  const int n = blockIdx.x * 256 + threadIdx.x;
  if (n >= NROWS) return;
  float s = 0.f;
  for (int j = 0; j < NBN2; ++j) s += partial[(size_t)j * NROWS + n];
  const float p = pcopy[n];
  scale[n] = (1.0f - p) / s;
  ofs[n]   = (1.0f - p) * 1e-20f;
}

// ---------------- kernel 4a: normalize from bf16 exp -> f32 out ----------------
__global__ __launch_bounds__(256) void norm_bf16_kernel(
    const u16* __restrict__ ebf, float* __restrict__ out,
    const float* __restrict__ scale, const float* __restrict__ ofs)
{
  const int total8 = NROWS * VOCAB / 8;     // VOCAB/8 = 4000
  const int stride = gridDim.x * blockDim.x;
  for (int i = blockIdx.x * 256 + threadIdx.x; i < total8; i += stride) {
    const int n = i / (VOCAB / 8);
    ushort4 v0 = ((const ushort4*)ebf)[i * 2];
    ushort4 v1 = ((const ushort4*)ebf)[i * 2 + 1];
    const float sc = scale[n], of = ofs[n];
    float4 o0, o1;
    o0.x = bf2f(v0.x) * sc + of; o0.y = bf2f(v0.y) * sc + of;
    o0.z = bf2f(v0.z) * sc + of; o0.w = bf2f(v0.w) * sc + of;
    o1.x = bf2f(v1.x) * sc + of; o1.y = bf2f(v1.y) * sc + of;
    o1.z = bf2f(v1.z) * sc + of; o1.w = bf2f(v1.w) * sc + of;
    ((float4*)out)[i * 2]     = o0;
    ((float4*)out)[i * 2 + 1] = o1;
  }
}

// ---------------- kernel 4b: normalize f32 in place (fallback) ----------------
__global__ __launch_bounds__(256) void norm_kernel(
    float* __restrict__ out, const float* __restrict__ scale,
    const float* __restrict__ ofs)
{
  const int total4 = NROWS * VOCAB / 4;
  const int stride = gridDim.x * blockDim.x;
  for (int i = blockIdx.x * 256 + threadIdx.x; i < total4; i += stride) {
    const int n = i / (VOCAB / 4);
    float4* p = (float4*)out + i;
    float4 v = *p;
    const float sc = scale[n], of = ofs[n];
    v.x = v.x * sc + of;
    v.y = v.y * sc + of;
    v.z = v.z * sc + of;
    v.w = v.w * sc + of;
    *p = v;
  }
}

// ---------------- kernel 5: scatter-add copy mass ----------------
__global__ __launch_bounds__(256) void scatter_kernel(
    float* __restrict__ out, const float* __restrict__ attn,
    const int* __restrict__ src, const float* __restrict__ pcopy)
{
  const int t = blockIdx.x * 256 + threadIdx.x;   // 65536 total
  const int n = t >> 6;
  const int s = t & 63;
  const int b = n & (BATCH - 1);
  const int v = src[s * BATCH + b];
  const float w = pcopy[n] * attn[(size_t)n * SLEN + s];
  atomicAdd(out + (size_t)n * VOCAB + v, w);
}

extern "C" void kernel_launch(void* const* d_in, const int* in_sizes, int n_in,
                              void* d_out, int out_size, void* d_ws, size_t ws_size,
                              hipStream_t stream) {
  const float* hidden = (const float*)d_in[0];
  const float* attn   = (const float*)d_in[1];
  const int*   src    = (const int*)d_in[2];
  const float* W      = (const float*)d_in[3];
  const float* w_copy = (const float*)d_in[4];
  const float* b_copy = (const float*)d_in[5];
  float* out = (float*)d_out;

  char* ws = (char*)d_ws;
  u8*    Wq      = (u8*)ws;                                    // 32,768,000 B
  u8*    hq      = (u8*)(ws + 32768000);                       //  1,048,576 B
  float* pcopy   = (float*)(ws + 33816576);                    //      4,096 B
  float* partial = (float*)(ws + 33820672);                    //  1,024,000 B
  float* scale   = (float*)(ws + 34844672);                    //      4,096 B
  float* ofs     = (float*)(ws + 34848768);                    //      4,096 B
  u16*   ebf     = (u16*)(ws + 34852864);                      // 65,536,000 B
  const size_t need_bf16 = 34852864ull + 65536000ull;
  const int use_bf16 = (ws_size >= need_bf16) ? 1 : 0;

  const int conv_blocks = (VOCAB * DDIM / 16 + 255) / 256;     // 8000
  prep_convw_kernel<<<NROWS + conv_blocks, 256, 0, stream>>>(
      hidden, w_copy, b_copy, hq, pcopy, W, Wq);
  gemm_exp_kernel<<<4 * NBN2, 512, 0, stream>>>(hq, Wq, out, ebf, partial, use_bf16);
  rowsum_kernel<<<(NROWS + 255) / 256, 256, 0, stream>>>(partial, pcopy, scale, ofs);
  if (use_bf16)
    norm_bf16_kernel<<<2048, 256, 0, stream>>>(ebf, out, scale, ofs);
  else
    norm_kernel<<<2048, 256, 0, stream>>>(out, scale, ofs);
  scatter_kernel<<<NROWS * SLEN / 256, 256, 0, stream>>>(out, attn, src, pcopy);
}